// Round 9
// baseline (550.247 us; speedup 1.0000x reference)
//
#include <hip/hip_runtime.h>

namespace {

typedef float f32x4 __attribute__((ext_vector_type(4)));

constexpr int H = 17, W = 17, NC = H * W;   // 289 cells
constexpr int SW = 20, SH = 19;             // LDS tile stride, 1-wide zero halo
constexpr int NT = 320;                     // 5 waves; critical SIMD carries 2 (TLP)

__device__ __forceinline__ float clip10(float v) {
    return fminf(fmaxf(v, -10.f), 10.f);
}
__device__ __forceinline__ float max3f(float a, float b, float c) {
    return fmaxf(fmaxf(a, b), c);   // v_max3_f32
}

__device__ __forceinline__ float scent_at(int hy, int wx, const float* __restrict__ food) {
    const float SK[5][5] = {
        {0.f,   .125f, .25f, .125f, 0.f},
        {.125f, .25f,  .5f,  .25f,  .125f},
        {.25f,  .5f,   1.f,  .5f,   .25f},
        {.125f, .25f,  .5f,  .25f,  .125f},
        {0.f,   .125f, .25f, .125f, 0.f}};
    float sc = 0.f;
    #pragma unroll
    for (int dy = -2; dy <= 2; ++dy) {
        #pragma unroll
        for (int dx = -2; dx <= 2; ++dx) {
            const float k = SK[dy + 2][dx + 2];
            if (k != 0.f) {
                const int yy = hy + dy, xx = wx + dx;
                if (yy >= 0 && yy < H && xx >= 0 && xx < W)
                    sc = fmaf(k, food[yy * W + xx], sc);
            }
        }
    }
    return sc;
}

// ---- manual VMEM pipeline primitives (weights stream, vmcnt-counted) ----
#define GLD4(dst, OFFSTR) \
    asm volatile("global_load_dwordx4 %0, %1, off offset:" OFFSTR \
                 : "=v"(dst) : "v"(wbase))
#define VWAIT(NSTR) do { \
    asm volatile("s_waitcnt vmcnt(" NSTR ")" ::: "memory"); \
    __builtin_amdgcn_sched_barrier(0); } while (0)

// one ReLU unit: h = relu(be + w·y); then delta accumulation
#define DO_O(WA, WB, WC, BEV) do {                                    \
    float a_ = (BEV);                                                 \
    a_ = fmaf((WA).x, y0, a_); a_ = fmaf((WA).y, y1, a_);             \
    a_ = fmaf((WA).z, y2, a_); a_ = fmaf((WA).w, y3, a_);             \
    a_ = fmaf((WB).x, y4, a_); a_ = fmaf((WB).y, y5, a_);             \
    a_ = fmaf((WB).z, y6, a_); a_ = fmaf((WB).w, y7, a_);             \
    a_ = fmaf((WC).x, y8, a_);                                        \
    a_ = fmaxf(a_, 0.f);                                              \
    d0 = fmaf((WC).y, a_, d0); d1 = fmaf((WC).z, a_, d1);             \
    d2 = fmaf((WC).w, a_, d2);                                        \
} while (0)

#define ISSUE_A(O0,O1,O2,O3,O4,O5,O6,O7,O8,O9,O10,O11) do {           \
    GLD4(a0,O0); GLD4(a1,O1); GLD4(a2,O2); GLD4(a3,O3);               \
    GLD4(a4,O4); GLD4(a5,O5); GLD4(a6,O6); GLD4(a7,O7);               \
    GLD4(a8,O8); GLD4(a9,O9); GLD4(a10,O10); GLD4(a11,O11); } while (0)
#define ISSUE_B(O0,O1,O2,O3,O4,O5,O6,O7,O8,O9,O10,O11) do {           \
    GLD4(b0,O0); GLD4(b1,O1); GLD4(b2,O2); GLD4(b3,O3);               \
    GLD4(b4q,O4); GLD4(b5,O5); GLD4(b6,O6); GLD4(b7,O7);              \
    GLD4(b8,O8); GLD4(b9,O9); GLD4(b10,O10); GLD4(b11,O11); } while (0)

// prep: pack 49 weight quads into d_ws (runs every launch; deterministic)
// quad layout per unit o: q[3o]   = {w3[o,0], w3[o,1], w3[o,2], w3[o,4]/8}
//                         q[3o+1] = {w3[o,5]/8, w3[o,6]/8, w3[o,8]/8, w3[o,9]/8}
//                         q[3o+2] = {w3[o,10]/8, w4[0,o], w4[1,o], w4[2,o]}
// q[48] = {b4[0], b4[1], b4[2], 0}
__global__ void prep_kernel(const float* __restrict__ w3,
                            const float* __restrict__ w4,
                            const float* __restrict__ b4,
                            float* __restrict__ ws)
{
    const int o = (int)threadIdx.x;
    f32x4* q = (f32x4*)ws;
    if (o < 16) {
        q[3*o]   = (f32x4){w3[o*12+0], w3[o*12+1], w3[o*12+2], w3[o*12+4]*0.125f};
        q[3*o+1] = (f32x4){w3[o*12+5]*0.125f, w3[o*12+6]*0.125f,
                           w3[o*12+8]*0.125f, w3[o*12+9]*0.125f};
        q[3*o+2] = (f32x4){w3[o*12+10]*0.125f, w4[o], w4[16+o], w4[32+o]};
    } else if (o == 16) {
        q[48] = (f32x4){b4[0], b4[1], b4[2], 0.f};
    }
}

__launch_bounds__(NT, 2)   // 2 waves/EU -> 256-VGPR cap
__global__ void ca_kernel(const float* __restrict__ cell_in,
                          const float* __restrict__ food,
                          const float* __restrict__ w3,
                          const float* __restrict__ b3,
                          const int* __restrict__ steps_p,
                          const float* __restrict__ wq,
                          float* __restrict__ out)
{
    __shared__ float2 c01[SH * SW];      // channels 0,1 packed (b64 taps)
    __shared__ float  c2s[SH * SW];      // channel 2
    __shared__ float  scs[SH * SW];      // scent (pre-loop only)
    __shared__ float  xb[SH * SW];       // x[0] exchange for post-alive maxpool
    __shared__ f32x4  be4v[4 * NT];      // per-cell folded bias, per-lane quads
    __shared__ float  red[NT];

    const int tid = (int)threadIdx.x;
    const int steps = steps_p[0];
    const bool act = tid < NC;
    const unsigned long long wbase = (unsigned long long)wq;

    for (int i = tid; i < SH * SW; i += NT) {
        c01[i] = make_float2(0.f, 0.f);
        c2s[i] = 0.f; scs[i] = 0.f; xb[i] = 0.f;
    }
    __syncthreads();

    const int hy = act ? tid / W : 0;
    const int wx = act ? tid % W : 0;
    const int idx = (hy + 1) * SW + wx + 1;

    // per-cell state centers live in registers across the whole loop
    float cur0 = 0.f, cur1 = 0.f, cur2 = 0.f, sc = 0.f;
    if (act) {
        cur0 = cell_in[tid];
        cur1 = cell_in[NC + tid];
        cur2 = cell_in[2 * NC + tid];
        sc   = scent_at(hy, wx, food);
        c01[idx] = make_float2(cur0, cur1);
        c2s[idx] = cur2;
        scs[idx] = sc;
    }
    __syncthreads();

    // fold loop-invariant scent perception into per-cell bias quads
    if (act) {
        const float s00 = scs[idx-SW-1], s01 = scs[idx-SW], s02 = scs[idx-SW+1];
        const float s10 = scs[idx-1],                       s12 = scs[idx+1];
        const float s20 = scs[idx+SW-1], s21 = scs[idx+SW], s22 = scs[idx+SW+1];
        const float dxs = ((s02-s00) + 2.f*(s12-s10) + (s22-s20)) * 0.125f;
        const float dys = ((s20+2.f*s21+s22) - (s00+2.f*s01+s02)) * 0.125f;
        float bt[16];
        #pragma unroll
        for (int o = 0; o < 16; ++o)
            bt[o] = fmaf(w3[o*12+3], sc, fmaf(w3[o*12+7], dxs,
                    fmaf(w3[o*12+11], dys, b3[o])));
        be4v[0*NT + tid] = (f32x4){bt[0],  bt[1],  bt[2],  bt[3]};
        be4v[1*NT + tid] = (f32x4){bt[4],  bt[5],  bt[6],  bt[7]};
        be4v[2*NT + tid] = (f32x4){bt[8],  bt[9],  bt[10], bt[11]};
        be4v[3*NT + tid] = (f32x4){bt[12], bt[13], bt[14], bt[15]};
    }
    __syncthreads();

    // ---- main loop: weights streamed from L1 via counted-vmcnt pipeline ----
    for (int s = 0; s < steps; ++s) {
        float n0 = 0.f, n1 = 0.f, n2 = 0.f;
        bool pre = false;
        if (act) {
            f32x4 a0,a1,a2,a3,a4,a5,a6,a7,a8,a9,a10,a11, ab4;
            f32x4 b0,b1,b2,b3q,b4q,b5,b6,b7,b8,b9,b10,b11;
            // issue chunk A (units 0-3) + b4 quad, then chunk B (units 4-7)
            ISSUE_A("0","16","32","48","64","80","96","112","128","144","160","176");
            GLD4(ab4, "768");
            GLD4(b0,"192"); GLD4(b1,"208"); GLD4(b2,"224"); GLD4(b3q,"240");
            GLD4(b4q,"256"); GLD4(b5,"272"); GLD4(b6,"288"); GLD4(b7,"304");
            GLD4(b8,"320"); GLD4(b9,"336"); GLD4(b10,"352"); GLD4(b11,"368");

            // stencil + per-cell bias (LDS / lgkmcnt — independent of vmcnt)
            const float2 t00 = c01[idx-SW-1], t01 = c01[idx-SW], t02 = c01[idx-SW+1];
            const float2 t10 = c01[idx-1],                       t12 = c01[idx+1];
            const float2 t20 = c01[idx+SW-1], t21 = c01[idx+SW], t22 = c01[idx+SW+1];
            const float r00 = c2s[idx-SW-1], r01 = c2s[idx-SW], r02 = c2s[idx-SW+1];
            const float r10 = c2s[idx-1],                       r12 = c2s[idx+1];
            const float r20 = c2s[idx+SW-1], r21 = c2s[idx+SW], r22 = c2s[idx+SW+1];
            const f32x4 bev0 = be4v[0*NT + tid], bev1 = be4v[1*NT + tid];
            const f32x4 bev2 = be4v[2*NT + tid], bev3 = be4v[3*NT + tid];

            const float y0 = cur0, y1 = cur1, y2 = cur2;
            const float y3 = (t02.x-t00.x) + 2.f*(t12.x-t10.x) + (t22.x-t20.x);
            const float y4 = (t02.y-t00.y) + 2.f*(t12.y-t10.y) + (t22.y-t20.y);
            const float y5 = (r02-r00) + 2.f*(r12-r10) + (r22-r20);
            const float y6 = (t20.x+2.f*t21.x+t22.x) - (t00.x+2.f*t01.x+t02.x);
            const float y7 = (t20.y+2.f*t21.y+t22.y) - (t00.y+2.f*t01.y+t02.y);
            const float y8 = (r20+2.f*r21+r22) - (r00+2.f*r01+r02);
            pre = max3f(max3f(t00.x,t01.x,t02.x), max3f(t10.x,cur0,t12.x),
                        max3f(t20.x,t21.x,t22.x)) > 0.1f;

            // chunk A ready (B's 12 still in flight)
            VWAIT("12");
            float d0 = ab4.x, d1 = ab4.y, d2 = ab4.z;
            DO_O(a0,a1,a2, bev0.x); DO_O(a3,a4,a5, bev0.y);
            DO_O(a6,a7,a8, bev0.z); DO_O(a9,a10,a11, bev0.w);
            ISSUE_A("384","400","416","432","448","464","480","496","512","528","544","560");
            VWAIT("12");
            DO_O(b0,b1,b2, bev1.x); DO_O(b3q,b4q,b5, bev1.y);
            DO_O(b6,b7,b8, bev1.z); DO_O(b9,b10,b11, bev1.w);
            GLD4(b0,"576"); GLD4(b1,"592"); GLD4(b2,"608"); GLD4(b3q,"624");
            GLD4(b4q,"640"); GLD4(b5,"656"); GLD4(b6,"672"); GLD4(b7,"688");
            GLD4(b8,"704"); GLD4(b9,"720"); GLD4(b10,"736"); GLD4(b11,"752");
            VWAIT("12");
            DO_O(a0,a1,a2, bev2.x); DO_O(a3,a4,a5, bev2.y);
            DO_O(a6,a7,a8, bev2.z); DO_O(a9,a10,a11, bev2.w);
            VWAIT("0");
            DO_O(b0,b1,b2, bev3.x); DO_O(b3q,b4q,b5, bev3.y);
            DO_O(b6,b7,b8, bev3.z); DO_O(b9,b10,b11, bev3.w);

            n0 = y0 + d0; n1 = y1 + d1; n2 = y2 + d2;
            xb[idx] = n0;
        }
        __syncthreads();
        if (act) {
            const float x00 = xb[idx-SW-1], x01 = xb[idx-SW], x02 = xb[idx-SW+1];
            const float x10 = xb[idx-1],                      x12 = xb[idx+1];
            const float x20 = xb[idx+SW-1], x21 = xb[idx+SW], x22 = xb[idx+SW+1];
            const float mx2 = max3f(max3f(x00,x01,x02), max3f(x10,n0,x12),
                                    max3f(x20,x21,x22));
            const float m = (pre && (mx2 > 0.1f)) ? 1.f : 0.f;
            cur0 = clip10(n0 * m);
            cur1 = clip10(n1 * m);
            cur2 = clip10(n2 * m);
            c01[idx] = make_float2(cur0, cur1);
            c2s[idx] = cur2;
        }
        __syncthreads();
    }

    // ---- outputs: cell (4*289) | food (289) | living_count (1) ----
    if (act) {
        out[tid]          = cur0;
        out[NC + tid]     = cur1;
        out[2 * NC + tid] = cur2;
        out[3 * NC + tid] = clip10(sc);
        out[4 * NC + tid] = food[tid];
        red[tid] = cur0;
    } else {
        red[tid] = 0.f;
    }
    __syncthreads();
    if (tid < 64) {
        float s2 = red[tid] + red[tid + 64] + red[tid + 128]
                 + red[tid + 192] + red[tid + 256];
        #pragma unroll
        for (int off = 32; off > 0; off >>= 1)
            s2 += __shfl_down(s2, off, 64);
        if (tid == 0) out[5 * NC] = s2;
    }
}

}  // namespace

extern "C" void kernel_launch(void* const* d_in, const int* in_sizes, int n_in,
                              void* d_out, int out_size, void* d_ws, size_t ws_size,
                              hipStream_t stream) {
    const float* cell = (const float*)d_in[0];
    const float* food = (const float*)d_in[1];
    const float* w3   = (const float*)d_in[2];
    const float* b3   = (const float*)d_in[3];
    const float* w4   = (const float*)d_in[4];
    const float* b4   = (const float*)d_in[5];
    const int*   st   = (const int*)d_in[6];
    float* out = (float*)d_out;
    float* ws  = (float*)d_ws;
    prep_kernel<<<1, 64, 0, stream>>>(w3, w4, b4, ws);
    ca_kernel<<<1, NT, 0, stream>>>(cell, food, w3, b3, st, ws, out);
}

// Round 11
// 333.936 us; speedup vs baseline: 1.6478x; 1.6478x over previous
//
#include <hip/hip_runtime.h>

namespace {

typedef float f32x4 __attribute__((ext_vector_type(4)));

constexpr int H = 17, W = 17, NC = H * W;   // 289 cells
constexpr int SW = 20, SH = 19;             // LDS tile stride, 1-wide zero halo
constexpr int HALF = 320;
constexpr int NT = 640;                     // 10 waves; 2 threads per cell

#define PINV(x) asm volatile("" : "+v"(x))   // pin scalar into VGPR
#define PINS(x) asm volatile("" : "+s"(x))   // pin scalar into SGPR (SGPR-resident input)

// legal uniform float -> SGPR move
__device__ __forceinline__ float to_sgpr(float v) {
    return __uint_as_float(__builtin_amdgcn_readfirstlane(__float_as_uint(v)));
}

__device__ __forceinline__ float clip10(float v) {
    return fminf(fmaxf(v, -10.f), 10.f);
}
__device__ __forceinline__ float max3f(float a, float b, float c) {
    return fmaxf(fmaxf(a, b), c);   // v_max3_f32
}

__device__ __forceinline__ float scent_at(int hy, int wx, const float* __restrict__ food) {
    const float SK[5][5] = {
        {0.f,   .125f, .25f, .125f, 0.f},
        {.125f, .25f,  .5f,  .25f,  .125f},
        {.25f,  .5f,   1.f,  .5f,   .25f},
        {.125f, .25f,  .5f,  .25f,  .125f},
        {0.f,   .125f, .25f, .125f, 0.f}};
    float sc = 0.f;
    #pragma unroll
    for (int dy = -2; dy <= 2; ++dy) {
        #pragma unroll
        for (int dx = -2; dx <= 2; ++dx) {
            const float k = SK[dy + 2][dx + 2];
            if (k != 0.f) {
                const int yy = hy + dy, xx = wx + dx;
                if (yy >= 0 && yy < H && xx >= 0 && xx < W)
                    sc = fmaf(k, food[yy * W + xx], sc);
            }
        }
    }
    return sc;
}

__launch_bounds__(NT, 2)
__global__ void ca_kernel(const float* __restrict__ cell_in,
                          const float* __restrict__ food,
                          const float* __restrict__ w3,
                          const float* __restrict__ b3,
                          const float* __restrict__ w4,
                          const float* __restrict__ b4,
                          const int* __restrict__ steps_p,
                          float* __restrict__ out)
{
    __shared__ f32x4 c012[SH * SW];    // {c0,c1,c2,-} state (b128 taps)
    __shared__ float scs[SH * SW];     // scent (pre-loop only)
    __shared__ float xb[SH * SW];      // x[0] exchange for post-alive maxpool
    __shared__ f32x4 pd[NT];           // per-half MLP partials {d0,d1,d2,-}
    __shared__ float red[NT];

    const int tid = (int)threadIdx.x;
    const int steps = steps_p[0];
    const bool hi = tid >= HALF;               // high half computes units 8..15
    const int ct = hi ? tid - HALF : tid;      // cell index
    const bool act = ct < NC;
    const int cc = act ? ct : 0;               // clamped (safe LDS idx for inactive)

    // zero LDS (halo zeros are decision-equivalent to -inf pad: 0.1 > 0)
    for (int i = tid; i < SH * SW; i += NT) {
        c012[i] = (f32x4){0.f, 0.f, 0.f, 0.f};
        scs[i] = 0.f; xb[i] = 0.f;
    }
    __syncthreads();

    const int hy = cc / W, wx = cc % W;
    const int idx = (hy + 1) * SW + wx + 1;

    // both halves keep the cell's state centers in registers
    float cur0 = 0.f, cur1 = 0.f, cur2 = 0.f, sc = 0.f;
    if (act) {
        cur0 = cell_in[ct];
        cur1 = cell_in[NC + ct];
        cur2 = cell_in[2 * NC + ct];
        sc   = scent_at(hy, wx, food);
        if (!hi) {
            c012[idx] = (f32x4){cur0, cur1, cur2, 0.f};
            scs[idx] = sc;
        }
    }
    __syncthreads();

    // ---- per-half weights: wp (9 cols) -> VGPR pins; w4 cols -> SGPRs ----
    const int ub = hi ? 8 : 0;                 // first unit of this half
    float wp[8][9], be[8];
    float w40[8], w41[8], w42[8];
    #pragma unroll
    for (int j = 0; j < 8; ++j) {
        const int o = ub + j;
        wp[j][0] = w3[o*12 + 0];
        wp[j][1] = w3[o*12 + 1];
        wp[j][2] = w3[o*12 + 2];
        wp[j][3] = w3[o*12 + 4] * 0.125f;
        wp[j][4] = w3[o*12 + 5] * 0.125f;
        wp[j][5] = w3[o*12 + 6] * 0.125f;
        wp[j][6] = w3[o*12 + 8] * 0.125f;
        wp[j][7] = w3[o*12 + 9] * 0.125f;
        wp[j][8] = w3[o*12 + 10] * 0.125f;
        // wave-uniform (hi is wave-uniform): legal readfirstlane -> SGPR
        w40[j] = to_sgpr(w4[ub + j]);
        w41[j] = to_sgpr(w4[16 + ub + j]);
        w42[j] = to_sgpr(w4[32 + ub + j]);
    }
    float b40 = hi ? 0.f : b4[0];              // only low half seeds the bias
    float b41 = hi ? 0.f : b4[1];
    float b42 = hi ? 0.f : b4[2];

    // fold loop-invariant scent perception into per-cell, per-half bias be[]
    {
        const float s00 = scs[idx-SW-1], s01 = scs[idx-SW], s02 = scs[idx-SW+1];
        const float s10 = scs[idx-1],                       s12 = scs[idx+1];
        const float s20 = scs[idx+SW-1], s21 = scs[idx+SW], s22 = scs[idx+SW+1];
        const float dxs = ((s02-s00) + 2.f*(s12-s10) + (s22-s20)) * 0.125f;
        const float dys = ((s20+2.f*s21+s22) - (s00+2.f*s01+s02)) * 0.125f;
        #pragma unroll
        for (int j = 0; j < 8; ++j) {
            const int o = ub + j;
            be[j] = fmaf(w3[o*12+3], sc, fmaf(w3[o*12+7], dxs,
                    fmaf(w3[o*12+11], dys, b3[o])));
        }
    }

    // pins: 72+8 VGPR scalars; 24 SGPR scalars (already SGPR-resident)
    #pragma unroll
    for (int j = 0; j < 8; ++j) {
        #pragma unroll
        for (int c = 0; c < 9; ++c) PINV(wp[j][c]);
        PINV(be[j]);
        PINS(w40[j]); PINS(w41[j]); PINS(w42[j]);
    }

    // ---- main loop: 3 barriers/step ----
    for (int s = 0; s < steps; ++s) {
        float d0 = b40, d1 = b41, d2 = b42;
        bool pre = false;
        if (act) {
            // Phase A: 8 f32x4 neighbor taps; centers from registers
            const f32x4 t00 = c012[idx-SW-1], t01 = c012[idx-SW], t02 = c012[idx-SW+1];
            const f32x4 t10 = c012[idx-1],                        t12 = c012[idx+1];
            const f32x4 t20 = c012[idx+SW-1], t21 = c012[idx+SW], t22 = c012[idx+SW+1];

            const float y0 = cur0, y1 = cur1, y2 = cur2;
            const float y3 = (t02.x-t00.x) + 2.f*(t12.x-t10.x) + (t22.x-t20.x);
            const float y4 = (t02.y-t00.y) + 2.f*(t12.y-t10.y) + (t22.y-t20.y);
            const float y5 = (t02.z-t00.z) + 2.f*(t12.z-t10.z) + (t22.z-t20.z);
            const float y6 = (t20.x+2.f*t21.x+t22.x) - (t00.x+2.f*t01.x+t02.x);
            const float y7 = (t20.y+2.f*t21.y+t22.y) - (t00.y+2.f*t01.y+t02.y);
            const float y8 = (t20.z+2.f*t21.z+t22.z) - (t00.z+2.f*t01.z+t02.z);
            pre = max3f(max3f(t00.x,t01.x,t02.x), max3f(t10.x,cur0,t12.x),
                        max3f(t20.x,t21.x,t22.x)) > 0.1f;

            #pragma unroll
            for (int j = 0; j < 8; ++j) {
                float a = be[j];
                a = fmaf(wp[j][0], y0, a); a = fmaf(wp[j][1], y1, a);
                a = fmaf(wp[j][2], y2, a); a = fmaf(wp[j][3], y3, a);
                a = fmaf(wp[j][4], y4, a); a = fmaf(wp[j][5], y5, a);
                a = fmaf(wp[j][6], y6, a); a = fmaf(wp[j][7], y7, a);
                a = fmaf(wp[j][8], y8, a);
                a = fmaxf(a, 0.f);
                d0 = fmaf(w40[j], a, d0);   // w4 from SGPR (1 SGPR/instr: legal)
                d1 = fmaf(w41[j], a, d1);
                d2 = fmaf(w42[j], a, d2);
            }
            pd[tid] = (f32x4){d0, d1, d2, 0.f};
        }
        __syncthreads();
        float n0 = 0.f, n1 = 0.f, n2 = 0.f;
        if (act) {
            // combine partner partials; both halves compute n identically
            const f32x4 pp = pd[hi ? tid - HALF : tid + HALF];
            n0 = cur0 + d0 + pp.x;
            n1 = cur1 + d1 + pp.y;
            n2 = cur2 + d2 + pp.z;
            if (!hi) xb[idx] = n0;
        }
        __syncthreads();
        if (act) {
            // Phase B: post-alive maxpool (center from register), mask, clip
            const float x00 = xb[idx-SW-1], x01 = xb[idx-SW], x02 = xb[idx-SW+1];
            const float x10 = xb[idx-1],                      x12 = xb[idx+1];
            const float x20 = xb[idx+SW-1], x21 = xb[idx+SW], x22 = xb[idx+SW+1];
            const float mx2 = max3f(max3f(x00,x01,x02), max3f(x10,n0,x12),
                                    max3f(x20,x21,x22));
            const float m = (pre && (mx2 > 0.1f)) ? 1.f : 0.f;
            cur0 = clip10(n0 * m);
            cur1 = clip10(n1 * m);
            cur2 = clip10(n2 * m);
            if (!hi) c012[idx] = (f32x4){cur0, cur1, cur2, 0.f};
        }
        __syncthreads();
    }

    // ---- outputs: cell (4*289) | food (289) | living_count (1) ----
    if (act && !hi) {
        out[ct]          = cur0;
        out[NC + ct]     = cur1;
        out[2 * NC + ct] = cur2;
        out[3 * NC + ct] = clip10(sc);
        out[4 * NC + ct] = food[ct];
        red[tid] = cur0;
    } else {
        red[tid] = 0.f;
    }
    __syncthreads();
    if (tid < 64) {
        float s2 = 0.f;
        #pragma unroll
        for (int k = 0; k < 10; ++k) s2 += red[tid + 64 * k];
        #pragma unroll
        for (int off = 32; off > 0; off >>= 1)
            s2 += __shfl_down(s2, off, 64);
        if (tid == 0) out[5 * NC] = s2;
    }
}

}  // namespace

extern "C" void kernel_launch(void* const* d_in, const int* in_sizes, int n_in,
                              void* d_out, int out_size, void* d_ws, size_t ws_size,
                              hipStream_t stream) {
    const float* cell = (const float*)d_in[0];
    const float* food = (const float*)d_in[1];
    const float* w3   = (const float*)d_in[2];
    const float* b3   = (const float*)d_in[3];
    const float* w4   = (const float*)d_in[4];
    const float* b4   = (const float*)d_in[5];
    const int*   st   = (const int*)d_in[6];
    float* out = (float*)d_out;
    ca_kernel<<<1, NT, 0, stream>>>(cell, food, w3, b3, w4, b4, st, out);
}

// Round 12
// 329.426 us; speedup vs baseline: 1.6703x; 1.0137x over previous
//
#include <hip/hip_runtime.h>

namespace {

typedef float f32x4 __attribute__((ext_vector_type(4)));

constexpr int H = 17, W = 17, NC = H * W;   // 289 cells
constexpr int SW = 20, SH = 19;             // LDS tile stride, 1-wide zero halo
constexpr int NT = 320;                     // 5 waves; critical SIMD carries 2 (TLP)

#define PIN(x) asm volatile("" : "+v"(x))

__device__ __forceinline__ float clip10(float v) {
    return fminf(fmaxf(v, -10.f), 10.f);
}
__device__ __forceinline__ float max3f(float a, float b, float c) {
    return fmaxf(fmaxf(a, b), c);   // v_max3_f32
}

__device__ __forceinline__ float scent_at(int hy, int wx, const float* __restrict__ food) {
    const float SK[5][5] = {
        {0.f,   .125f, .25f, .125f, 0.f},
        {.125f, .25f,  .5f,  .25f,  .125f},
        {.25f,  .5f,   1.f,  .5f,   .25f},
        {.125f, .25f,  .5f,  .25f,  .125f},
        {0.f,   .125f, .25f, .125f, 0.f}};
    float sc = 0.f;
    #pragma unroll
    for (int dy = -2; dy <= 2; ++dy) {
        #pragma unroll
        for (int dx = -2; dx <= 2; ++dx) {
            const float k = SK[dy + 2][dx + 2];
            if (k != 0.f) {
                const int yy = hy + dy, xx = wx + dx;
                if (yy >= 0 && yy < H && xx >= 0 && xx < W)
                    sc = fmaf(k, food[yy * W + xx], sc);
            }
        }
    }
    return sc;
}

// 9 taps from a padded SoA float array (conflict-light b32 reads)
#define LOAD9(ARR, IDX, T)                                                        \
    const float T##00 = ARR[(IDX)-SW-1], T##01 = ARR[(IDX)-SW], T##02 = ARR[(IDX)-SW+1], \
                T##10 = ARR[(IDX)-1],    T##11 = ARR[(IDX)],    T##12 = ARR[(IDX)+1],    \
                T##20 = ARR[(IDX)+SW-1], T##21 = ARR[(IDX)+SW], T##22 = ARR[(IDX)+SW+1];

// prep: pack 49 pre-scaled weight quads into d_ws.
// quad layout per unit o: q[3o]   = {w3[o,0], w3[o,1], w3[o,2], w3[o,4]/8}
//                         q[3o+1] = {w3[o,5]/8, w3[o,6]/8, w3[o,8]/8, w3[o,9]/8}
//                         q[3o+2] = {w3[o,10]/8, w4[0,o], w4[1,o], w4[2,o]}
// q[48] = {b4[0], b4[1], b4[2], 0}
__global__ void prep_kernel(const float* __restrict__ w3,
                            const float* __restrict__ w4,
                            const float* __restrict__ b4,
                            float* __restrict__ ws)
{
    const int o = (int)threadIdx.x;
    f32x4* q = (f32x4*)ws;
    if (o < 16) {
        q[3*o]   = (f32x4){w3[o*12+0], w3[o*12+1], w3[o*12+2], w3[o*12+4]*0.125f};
        q[3*o+1] = (f32x4){w3[o*12+5]*0.125f, w3[o*12+6]*0.125f,
                           w3[o*12+8]*0.125f, w3[o*12+9]*0.125f};
        q[3*o+2] = (f32x4){w3[o*12+10]*0.125f, w4[o], w4[16+o], w4[32+o]};
    } else if (o == 16) {
        q[48] = (f32x4){b4[0], b4[1], b4[2], 0.f};
    }
}

__launch_bounds__(NT, 2)
__global__ void ca_kernel(const float* __restrict__ cell_in,
                          const float* __restrict__ food,
                          const float* __restrict__ w3,
                          const float* __restrict__ b3,
                          const int* __restrict__ steps_p,
                          const float* __restrict__ wq,
                          float* __restrict__ out)
{
    __shared__ float c0s[SH * SW];
    __shared__ float c1s[SH * SW];
    __shared__ float c2s[SH * SW];
    __shared__ float scs[SH * SW];   // scent (pre-loop only)
    __shared__ float xb[SH * SW];    // x[0] exchange for post-alive maxpool
    __shared__ float red[NT];

    const int tid = (int)threadIdx.x;
    const int steps = steps_p[0];
    const bool act = tid < NC;
    const f32x4* __restrict__ q = (const f32x4*)wq;

    // zero LDS (halo zeros are decision-equivalent to -inf pad: threshold 0.1 > 0)
    for (int i = tid; i < SH * SW; i += NT) {
        c0s[i] = 0.f; c1s[i] = 0.f; c2s[i] = 0.f; scs[i] = 0.f; xb[i] = 0.f;
    }
    __syncthreads();

    const int hy = act ? tid / W : 0;
    const int wx = act ? tid % W : 0;
    const int idx = (hy + 1) * SW + wx + 1;

    // per-cell state centers live in registers across the whole loop
    float cur0 = 0.f, cur1 = 0.f, cur2 = 0.f, sc = 0.f;
    if (act) {
        cur0 = cell_in[tid];
        cur1 = cell_in[NC + tid];
        cur2 = cell_in[2 * NC + tid];
        sc   = scent_at(hy, wx, food);
        c0s[idx] = cur0;
        c1s[idx] = cur1;
        c2s[idx] = cur2;
        scs[idx] = sc;
    }
    __syncthreads();

    // ---- fold loop-invariant scent perception into per-cell bias be[] ----
    float be[16];
    {
        LOAD9(scs, idx, s)
        const float dxs = ((s02-s00) + 2.f*(s12-s10) + (s22-s20)) * 0.125f;
        const float dys = ((s20+2.f*s21+s22) - (s00+2.f*s01+s02)) * 0.125f;
        #pragma unroll
        for (int o = 0; o < 16; ++o)
            be[o] = fmaf(w3[o*12+3], s11, fmaf(w3[o*12+7], dxs,
                    fmaf(w3[o*12+11], dys, b3[o])));
    }
    #pragma unroll
    for (int o = 0; o < 16; ++o) PIN(be[o]);

    // ---- main loop: 2 barriers/step; weights re-fetched per step as 13
    //      uniform b128 loads (single L1 transaction each; allocator holds
    //      only ~12 transient regs -> nothing long-lived to spill) ----
    for (int s = 0; s < steps; ++s) {
        float n0 = 0.f, n1 = 0.f, n2 = 0.f;
        bool pre = false;
        if (act) {
            LOAD9(c0s, idx, p) LOAD9(c1s, idx, a) LOAD9(c2s, idx, r)
            const float y0 = cur0, y1 = cur1, y2 = cur2;
            const float y3 = (p02-p00) + 2.f*(p12-p10) + (p22-p20);
            const float y4 = (a02-a00) + 2.f*(a12-a10) + (a22-a20);
            const float y5 = (r02-r00) + 2.f*(r12-r10) + (r22-r20);
            const float y6 = (p20+2.f*p21+p22) - (p00+2.f*p01+p02);
            const float y7 = (a20+2.f*a21+a22) - (a00+2.f*a01+a02);
            const float y8 = (r20+2.f*r21+r22) - (r00+2.f*r01+r02);
            pre = max3f(max3f(p00,p01,p02), max3f(p10,cur0,p12),
                        max3f(p20,p21,p22)) > 0.1f;

            const f32x4 bq = q[48];
            float d0 = bq.x, d1 = bq.y, d2 = bq.z;
            #pragma unroll
            for (int o = 0; o < 16; ++o) {
                const f32x4 qa = q[3*o], qb = q[3*o+1], qc = q[3*o+2];
                float h = be[o];
                h = fmaf(qa.x, y0, h); h = fmaf(qa.y, y1, h);
                h = fmaf(qa.z, y2, h); h = fmaf(qa.w, y3, h);
                h = fmaf(qb.x, y4, h); h = fmaf(qb.y, y5, h);
                h = fmaf(qb.z, y6, h); h = fmaf(qb.w, y7, h);
                h = fmaf(qc.x, y8, h);
                h = fmaxf(h, 0.f);
                d0 = fmaf(qc.y, h, d0);
                d1 = fmaf(qc.z, h, d1);
                d2 = fmaf(qc.w, h, d2);
            }
            n0 = y0 + d0; n1 = y1 + d1; n2 = y2 + d2;
            xb[idx] = n0;
        }
        __syncthreads();
        if (act) {
            // post-alive maxpool; center tap n0 from register (8 LDS taps)
            const float x00 = xb[idx-SW-1], x01 = xb[idx-SW], x02 = xb[idx-SW+1];
            const float x10 = xb[idx-1],                      x12 = xb[idx+1];
            const float x20 = xb[idx+SW-1], x21 = xb[idx+SW], x22 = xb[idx+SW+1];
            const float mx2 = max3f(max3f(x00,x01,x02), max3f(x10,n0,x12),
                                    max3f(x20,x21,x22));
            const float m = (pre && (mx2 > 0.1f)) ? 1.f : 0.f;
            cur0 = clip10(n0 * m);
            cur1 = clip10(n1 * m);
            cur2 = clip10(n2 * m);
            c0s[idx] = cur0;
            c1s[idx] = cur1;
            c2s[idx] = cur2;
        }
        __syncthreads();
    }

    // ---- outputs: cell (4*289) | food (289) | living_count (1) ----
    if (act) {
        out[tid]          = cur0;
        out[NC + tid]     = cur1;
        out[2 * NC + tid] = cur2;
        out[3 * NC + tid] = clip10(sc);
        out[4 * NC + tid] = food[tid];
        red[tid] = cur0;
    } else {
        red[tid] = 0.f;
    }
    __syncthreads();
    if (tid < 64) {
        float s2 = red[tid] + red[tid + 64] + red[tid + 128]
                 + red[tid + 192] + red[tid + 256];
        #pragma unroll
        for (int off = 32; off > 0; off >>= 1)
            s2 += __shfl_down(s2, off, 64);
        if (tid == 0) out[5 * NC] = s2;
    }
}

}  // namespace

extern "C" void kernel_launch(void* const* d_in, const int* in_sizes, int n_in,
                              void* d_out, int out_size, void* d_ws, size_t ws_size,
                              hipStream_t stream) {
    const float* cell = (const float*)d_in[0];
    const float* food = (const float*)d_in[1];
    const float* w3   = (const float*)d_in[2];
    const float* b3   = (const float*)d_in[3];
    const float* w4   = (const float*)d_in[4];
    const float* b4   = (const float*)d_in[5];
    const int*   st   = (const int*)d_in[6];
    float* out = (float*)d_out;
    float* ws  = (float*)d_ws;
    prep_kernel<<<1, 64, 0, stream>>>(w3, w4, b4, ws);
    ca_kernel<<<1, NT, 0, stream>>>(cell, food, w3, b3, st, ws, out);
}